// Round 1
// 389.930 us; speedup vs baseline: 1.0018x; 1.0018x over previous
//
#include <hip/hip_runtime.h>
#include <cstdint>
#include <cstddef>

// ---------------------------------------------------------------------------
// QuantumRLAgent: 18-qubit statevector sim + MLPs.
// Batch collapses into ONE statevector. Dominant cost: two 524288x64 fp32
// matvecs (268 MB weight stream; LLC serves ~half across graph replays ->
// ~133 MB HBM fetch). Circuit: fused 1q gates; CNOT chain == perm
// P(i)=(i^(i<<1))&0x3FFFF fused into next kernel's gather; layer-1 analytic
// product state.
//
// R4 -> R5: named-float4-loads failed AGAIN to produce in-flight loads
// (VGPR=36 proves re-roll; demand BW 2.6 TB/s, VALUBusy 1.6% == pure
// latency bound). Stop fighting the C-level scheduler: inline-asm
// global_load_dwordx4 with counted s_waitcnt vmcnt(8) software pipeline,
// 2 groups x 8 loads in flight (16 KB/wave). Waits carry "+v" ties on the
// destination regs (data-dep fence) + sched_barrier(0) per guide rule #18.
// ---------------------------------------------------------------------------

#define NQb   18
#define DIMSZ 262144      // 2^18
#define PMASK 0x3FFFF
#define XLEN  73728       // 4096*18

typedef float2 cplx;
typedef float f4 __attribute__((ext_vector_type(4)));

__device__ __forceinline__ cplx cmul(cplx a, cplx b) {
  return make_float2(a.x*b.x - a.y*b.y, a.x*b.y + a.y*b.x);
}
__device__ __forceinline__ cplx cadd(cplx a, cplx b) {
  return make_float2(a.x + b.x, a.y + b.y);
}

// --------------------------------------------------------------------------
// K_prep: fused U = Rz*Ry*Rx per (layer,qubit); layer-0 product tables;
// zero accumulators (dots_rep[32][128] + xn2 + L2acc).
// --------------------------------------------------------------------------
__global__ void k_prep(const float* __restrict__ qp, cplx* __restrict__ Ug,
                       cplx* __restrict__ prodLow, cplx* __restrict__ prodHigh,
                       float* __restrict__ accs) {
  __shared__ cplx Ush[54][4];
  int t = threadIdx.x;
  for (int k = t; k < 4352; k += 256) accs[k] = 0.0f;
  if (t < 54) {
    float a = qp[t*3+0], b = qp[t*3+1], c = qp[t*3+2];
    float ca = cosf(0.5f*a), sa = sinf(0.5f*a);
    float cb = cosf(0.5f*b), sb = sinf(0.5f*b);
    float cc = cosf(0.5f*c), sc = sinf(0.5f*c);
    // M = Ry*Rx
    cplx m00 = make_float2( cb*ca,  sb*sa);
    cplx m01 = make_float2(-sb*ca, -cb*sa);
    cplx m10 = make_float2( sb*ca, -cb*sa);
    cplx m11 = make_float2( cb*ca, -sb*sa);
    // U = Rz*M : row0 *= e^{-ic/2}, row1 *= e^{+ic/2}
    cplx e0 = make_float2(cc, -sc), e1 = make_float2(cc, sc);
    cplx u00 = cmul(e0, m00), u01 = cmul(e0, m01);
    cplx u10 = cmul(e1, m10), u11 = cmul(e1, m11);
    Ush[t][0] = u00; Ush[t][1] = u01; Ush[t][2] = u10; Ush[t][3] = u11;
    Ug[t*4+0] = u00; Ug[t*4+1] = u01; Ug[t*4+2] = u10; Ug[t*4+3] = u11;
  }
  __syncthreads();
  // layer-0 product state: amp(i) = prod_p U0[17-p][bit_p(i)][0]
  for (int m = t; m < 4096; m += blockDim.x) {
    cplx v = make_float2(1.f, 0.f);
    for (int p = 0; p < 12; ++p) {
      int q = 17 - p;
      cplx f = ((m >> p) & 1) ? Ush[q][2] : Ush[q][0];
      v = cmul(v, f);
    }
    prodLow[m] = v;
  }
  if (t < 64) {
    cplx v = make_float2(1.f, 0.f);
    for (int p = 12; p < 18; ++p) {
      int q = 17 - p;
      cplx f = ((t >> (p - 12)) & 1) ? Ush[q][2] : Ush[q][0];
      v = cmul(v, f);
    }
    prodHigh[t] = v;
  }
}

// --------------------------------------------------------------------------
// K_enc: h = relu(state@w1+b1); enc = h@w2+b2; xc = amp*exp(i*ph).
// 1024 blocks x 256 threads, 4 rows/block, 4 independent accumulators.
// --------------------------------------------------------------------------
__global__ __launch_bounds__(256) void k_enc(
    const float* __restrict__ state, const float* __restrict__ w1,
    const float* __restrict__ b1, const float* __restrict__ w2,
    const float* __restrict__ b2, float* __restrict__ xRe,
    float* __restrict__ xIm, float* __restrict__ xn2) {
  __shared__ float sState[4][256];
  __shared__ float hS[4][64];
  __shared__ float encS[4][36];
  __shared__ float wsum[4];
  int t = threadIdx.x;
  int r = t >> 6, j = t & 63;
  const float4* st4 =
      reinterpret_cast<const float4*>(state + (size_t)blockIdx.x * 1024);
  reinterpret_cast<float4*>(&sState[0][0])[t] = st4[t];
  __syncthreads();
  float a0 = 0.f, a1 = 0.f, a2 = 0.f, a3 = 0.f;
#pragma unroll 4
  for (int k = 0; k < 256; k += 4) {
    a0 = fmaf(sState[r][k+0], w1[(k+0)*64 + j], a0);
    a1 = fmaf(sState[r][k+1], w1[(k+1)*64 + j], a1);
    a2 = fmaf(sState[r][k+2], w1[(k+2)*64 + j], a2);
    a3 = fmaf(sState[r][k+3], w1[(k+3)*64 + j], a3);
  }
  hS[r][j] = fmaxf((a0 + a1) + (a2 + a3) + b1[j], 0.f);
  __syncthreads();
  if (j < 36) {
    float a = b2[j];
#pragma unroll 8
    for (int k = 0; k < 64; ++k) a = fmaf(hS[r][k], w2[k*36 + j], a);
    encS[r][j] = a;
  }
  __syncthreads();
  float lsum = 0.f;
  if (j < 18) {
    float amp = encS[r][j], ph = encS[r][18 + j];
    float sp, cp;
    sincosf(ph, &sp, &cp);
    int row = blockIdx.x*4 + r;
    xRe[row*18 + j] = amp * cp;
    xIm[row*18 + j] = amp * sp;
    lsum = amp * amp;
  }
  for (int off = 32; off > 0; off >>= 1) lsum += __shfl_down(lsum, off, 64);
  if (j == 0) wsum[r] = lsum;
  __syncthreads();
  if (t == 0) atomicAdd(xn2, wsum[0] + wsum[1] + wsum[2] + wsum[3]);
}

// --------------------------------------------------------------------------
// K_gatesLow: gates on bits 0..9 (qubits 17..8). 256 blocks x 512 thr,
// contiguous 1024-elem tiles in LDS. Input gathered through perm P.
// mode 0: layer-0 product state; mode 1: svIn[P(i)].
// --------------------------------------------------------------------------
__global__ __launch_bounds__(512) void k_gatesLow(
    const cplx* __restrict__ Ug, const cplx* __restrict__ prodLow,
    const cplx* __restrict__ prodHigh, const cplx* __restrict__ svIn,
    cplx* __restrict__ svOut, int layer, int mode) {
  __shared__ float sRe[1024], sIm[1024];
  int t = threadIdx.x;
  int base = blockIdx.x << 10;
  for (int e = t; e < 1024; e += 512) {
    int i = base + e;
    int src = (i ^ (i << 1)) & PMASK;   // CNOT-chain permutation
    cplx v;
    if (mode == 0) v = cmul(prodHigh[src >> 12], prodLow[src & 4095]);
    else           v = svIn[src];
    sRe[e] = v.x; sIm[e] = v.y;
  }
  __syncthreads();
  for (int p = 0; p < 10; ++p) {
    int q = 17 - p;
    const cplx* U = Ug + (layer*18 + q)*4;
    cplx u00 = U[0], u01 = U[1], u10 = U[2], u11 = U[3];
    {
      int k = t;
      int i0 = ((k >> p) << (p + 1)) | (k & ((1 << p) - 1));
      int i1 = i0 | (1 << p);
      cplx a = make_float2(sRe[i0], sIm[i0]);
      cplx b = make_float2(sRe[i1], sIm[i1]);
      cplx na = cadd(cmul(u00, a), cmul(u01, b));
      cplx nb = cadd(cmul(u10, a), cmul(u11, b));
      sRe[i0] = na.x; sIm[i0] = na.y;
      sRe[i1] = nb.x; sIm[i1] = nb.y;
    }
    __syncthreads();
  }
  for (int e = t; e < 1024; e += 512)
    svOut[base + e] = make_float2(sRe[e], sIm[e]);
}

// --------------------------------------------------------------------------
// K_gatesHigh: gates on bits 10..17 (qubits 7..0). 256 blocks x 512 thr.
// Tile = 256 h-values (bits 10..17) x 4 l-values; in-place (tiles partition
// by l-chunk). LDS index m = h*4 + j.
// --------------------------------------------------------------------------
__global__ __launch_bounds__(512) void k_gatesHigh(
    const cplx* __restrict__ Ug, cplx* __restrict__ sv, int layer) {
  __shared__ float tRe[1024], tIm[1024];
  int t = threadIdx.x;
  int l0 = blockIdx.x << 2;
  for (int e = t; e < 1024; e += 512) {
    int h = e >> 2, j = e & 3;
    cplx v = sv[h*1024 + l0 + j];
    tRe[e] = v.x; tIm[e] = v.y;
  }
  __syncthreads();
  for (int ph = 0; ph < 8; ++ph) {
    int q = 7 - ph;                    // bit p = 10+ph, qubit q = 17-p
    const cplx* U = Ug + (layer*18 + q)*4;
    cplx u00 = U[0], u01 = U[1], u10 = U[2], u11 = U[3];
    {
      int kh = t >> 2, j = t & 3;
      int h0 = ((kh >> ph) << (ph + 1)) | (kh & ((1 << ph) - 1));
      int h1 = h0 | (1 << ph);
      int i0 = h0*4 + j, i1 = h1*4 + j;
      cplx a = make_float2(tRe[i0], tIm[i0]);
      cplx b = make_float2(tRe[i1], tIm[i1]);
      cplx na = cadd(cmul(u00, a), cmul(u01, b));
      cplx nb = cadd(cmul(u10, a), cmul(u11, b));
      tRe[i0] = na.x; tIm[i0] = na.y;
      tRe[i1] = nb.x; tIm[i1] = nb.y;
    }
    __syncthreads();
  }
  for (int e = t; e < 1024; e += 512) {
    int h = e >> 2, j = e & 3;
    sv[h*1024 + l0 + j] = make_float2(tRe[e], tIm[e]);
  }
}

// --------------------------------------------------------------------------
// K_combine: final perm gather + add normalized x + build cl (re plane,
// im plane; unnormalized) + accumulate L2 = ||sv||^2.
// --------------------------------------------------------------------------
__global__ __launch_bounds__(256) void k_combine(
    const cplx* __restrict__ svIn, const float* __restrict__ xRe,
    const float* __restrict__ xIm, const float* __restrict__ xn2,
    float* __restrict__ cl, float* __restrict__ L2acc) {
  int t = threadIdx.x;
  float xs = xn2[0];
  float invXn = (xs > 0.f) ? (1.0f / sqrtf(xs)) : 1.0f;
  float lsum = 0.f;
  for (int u = 0; u < 4; ++u) {
    int i = blockIdx.x*1024 + u*256 + t;
    int src = (i ^ (i << 1)) & PMASK;
    cplx v = svIn[src];
    if (i < XLEN) {
      v.x = fmaf(xRe[i], invXn, v.x);
      v.y = fmaf(xIm[i], invXn, v.y);
    }
    cl[i] = v.x;
    cl[DIMSZ + i] = v.y;
    lsum += v.x*v.x + v.y*v.y;
  }
  for (int off = 32; off > 0; off >>= 1) lsum += __shfl_down(lsum, off, 64);
  if ((t & 63) == 0) atomicAdd(L2acc, lsum);
}

// --------------------------------------------------------------------------
// K_matvec: partial[slot][mat*64+c] += sum_r cl[r]*W[r,c] over a 512-row
// chunk. 2048 blocks (1024 chunks x 2 mats).
//
// R5: inline-asm software pipeline. Two groups of 8 global_load_dwordx4 in
// flight (16 KB/wave). Counted waits: vmcnt(8) retires exactly the older
// group; vmcnt never drains to 0 until the tail. Waits carry "+v" ties on
// the 8 destination regs (hard data-dep: FMAs cannot be hoisted above the
// wait) + sched_barrier(0) (rule #18). Volatile asm order fixes the vmcnt
// arithmetic. Needed in-flight for 6.3 TB/s: ~10 KB/CU; this gives >100 KB.
// --------------------------------------------------------------------------
#define GLOAD(dst, ptr) \
  asm volatile("global_load_dwordx4 %0, %1, off" : "=v"(dst) : "v"(ptr))

#define VMWAIT(N, x0,x1,x2,x3,x4,x5,x6,x7) do {                      \
    asm volatile("s_waitcnt vmcnt(" #N ")"                           \
        : "+v"(x0), "+v"(x1), "+v"(x2), "+v"(x3),                    \
          "+v"(x4), "+v"(x5), "+v"(x6), "+v"(x7));                   \
    __builtin_amdgcn_sched_barrier(0);                               \
  } while (0)

#define CONSUME(g, w0,w1,w2,w3,w4,w5,w6,w7) do {                     \
    const int rr = (g)*128 + ro;                                     \
    float s0 = clS[rr+  0], s1 = clS[rr+ 16];                        \
    float s2 = clS[rr+ 32], s3 = clS[rr+ 48];                        \
    float s4 = clS[rr+ 64], s5 = clS[rr+ 80];                        \
    float s6 = clS[rr+ 96], s7 = clS[rr+112];                        \
    ax = fmaf(s0, w0[0], ax); ay = fmaf(s0, w0[1], ay);              \
    az = fmaf(s0, w0[2], az); aw = fmaf(s0, w0[3], aw);              \
    ax = fmaf(s1, w1[0], ax); ay = fmaf(s1, w1[1], ay);              \
    az = fmaf(s1, w1[2], az); aw = fmaf(s1, w1[3], aw);              \
    ax = fmaf(s2, w2[0], ax); ay = fmaf(s2, w2[1], ay);              \
    az = fmaf(s2, w2[2], az); aw = fmaf(s2, w2[3], aw);              \
    ax = fmaf(s3, w3[0], ax); ay = fmaf(s3, w3[1], ay);              \
    az = fmaf(s3, w3[2], az); aw = fmaf(s3, w3[3], aw);              \
    ax = fmaf(s4, w4[0], ax); ay = fmaf(s4, w4[1], ay);              \
    az = fmaf(s4, w4[2], az); aw = fmaf(s4, w4[3], aw);              \
    ax = fmaf(s5, w5[0], ax); ay = fmaf(s5, w5[1], ay);              \
    az = fmaf(s5, w5[2], az); aw = fmaf(s5, w5[3], aw);              \
    ax = fmaf(s6, w6[0], ax); ay = fmaf(s6, w6[1], ay);              \
    az = fmaf(s6, w6[2], az); aw = fmaf(s6, w6[3], aw);              \
    ax = fmaf(s7, w7[0], ax); ay = fmaf(s7, w7[1], ay);              \
    az = fmaf(s7, w7[2], az); aw = fmaf(s7, w7[3], aw);              \
  } while (0)

__global__ __launch_bounds__(256) void k_matvec(
    const float* __restrict__ cl, const float* __restrict__ Wdec,
    const float* __restrict__ Wval, float* __restrict__ dots_rep) {
  __shared__ float clS[512];
  __shared__ float red[1024];
  int t = threadIdx.x;
  int mat = blockIdx.x & 1;
  int chunk = blockIdx.x >> 1;             // 0..1023
  size_t r0 = (size_t)chunk * 512;
  if (t < 128)
    reinterpret_cast<float4*>(clS)[t] =
        reinterpret_cast<const float4*>(cl + r0)[t];
  __syncthreads();
  const float* Wb = (mat ? Wval : Wdec) + r0*64 + (size_t)((t & 15)*4);
  const int ro = t >> 4;
  // 8 row-phase base pointers (row stride within a group = 16 rows = 1024 f)
  const float* p0 = Wb + (size_t)ro * 64;
  const float* p1 = p0 + 1024;
  const float* p2 = p0 + 2048;
  const float* p3 = p0 + 3072;
  const float* p4 = p0 + 4096;
  const float* p5 = p0 + 5120;
  const float* p6 = p0 + 6144;
  const float* p7 = p0 + 7168;
  float ax = 0.f, ay = 0.f, az = 0.f, aw = 0.f;
  f4 A0, A1, A2, A3, A4, A5, A6, A7;
  f4 B0, B1, B2, B3, B4, B5, B6, B7;
  // group stride = 128 rows = 8192 floats
  // ---- prologue: issue g0, g1 (16 loads in flight) ----
  GLOAD(A0, p0);        GLOAD(A1, p1);        GLOAD(A2, p2);
  GLOAD(A3, p3);        GLOAD(A4, p4);        GLOAD(A5, p5);
  GLOAD(A6, p6);        GLOAD(A7, p7);
  GLOAD(B0, p0 + 8192); GLOAD(B1, p1 + 8192); GLOAD(B2, p2 + 8192);
  GLOAD(B3, p3 + 8192); GLOAD(B4, p4 + 8192); GLOAD(B5, p5 + 8192);
  GLOAD(B6, p6 + 8192); GLOAD(B7, p7 + 8192);
  // ---- g0: wait for A (B stays in flight), consume, refill A with g2 ----
  VMWAIT(8, A0, A1, A2, A3, A4, A5, A6, A7);
  CONSUME(0, A0, A1, A2, A3, A4, A5, A6, A7);
  GLOAD(A0, p0 + 16384); GLOAD(A1, p1 + 16384); GLOAD(A2, p2 + 16384);
  GLOAD(A3, p3 + 16384); GLOAD(A4, p4 + 16384); GLOAD(A5, p5 + 16384);
  GLOAD(A6, p6 + 16384); GLOAD(A7, p7 + 16384);
  // ---- g1: wait for B, consume, refill B with g3 ----
  VMWAIT(8, B0, B1, B2, B3, B4, B5, B6, B7);
  CONSUME(1, B0, B1, B2, B3, B4, B5, B6, B7);
  GLOAD(B0, p0 + 24576); GLOAD(B1, p1 + 24576); GLOAD(B2, p2 + 24576);
  GLOAD(B3, p3 + 24576); GLOAD(B4, p4 + 24576); GLOAD(B5, p5 + 24576);
  GLOAD(B6, p6 + 24576); GLOAD(B7, p7 + 24576);
  // ---- g2 ----
  VMWAIT(8, A0, A1, A2, A3, A4, A5, A6, A7);
  CONSUME(2, A0, A1, A2, A3, A4, A5, A6, A7);
  // ---- g3 (tail: drain) ----
  VMWAIT(0, B0, B1, B2, B3, B4, B5, B6, B7);
  CONSUME(3, B0, B1, B2, B3, B4, B5, B6, B7);

  red[t*4+0] = ax; red[t*4+1] = ay; red[t*4+2] = az; red[t*4+3] = aw;
  __syncthreads();
  if (t < 64) {
    int ci0 = t >> 2, jj = t & 3;
    float sum = 0.f;
#pragma unroll
    for (int r2 = 0; r2 < 16; ++r2) sum += red[(r2*16 + ci0)*4 + jj];
    int slot = chunk & 31;
    atomicAdd(&dots_rep[slot*128 + mat*64 + t], sum);
  }
}

// --------------------------------------------------------------------------
// K_final: sum 32 slots, apply invL, hidden relu + tiny second layers.
// --------------------------------------------------------------------------
__global__ void k_final(const float* __restrict__ dots_rep,
                        const float* __restrict__ L2acc,
                        const float* __restrict__ db1,
                        const float* __restrict__ dw2,
                        const float* __restrict__ db2,
                        const float* __restrict__ vb1,
                        const float* __restrict__ vw2,
                        const float* __restrict__ vb2,
                        float* __restrict__ out) {
  __shared__ float hd[64], hv[64];
  int t = threadIdx.x;
  float sd = 0.f, sva = 0.f;
#pragma unroll
  for (int s = 0; s < 32; ++s) {
    sd  += dots_rep[s*128 + t];
    sva += dots_rep[s*128 + 64 + t];
  }
  float invL = 1.0f / sqrtf(L2acc[0]);
  hd[t] = fmaxf(sd * invL + db1[t], 0.f);
  hv[t] = fmaxf(sva * invL + vb1[t], 0.f);
  __syncthreads();
  if (t < 18) {
    float s = db2[t];
    for (int k = 0; k < 64; ++k) s = fmaf(hd[k], dw2[k*18 + t], s);
    out[t] = s;
  }
  if (t == 20) {
    float s = vb2[0];
    for (int k = 0; k < 64; ++k) s = fmaf(hv[k], vw2[k], s);
    out[18] = s;
  }
}

extern "C" void kernel_launch(void* const* d_in, const int* in_sizes, int n_in,
                              void* d_out, int out_size, void* d_ws,
                              size_t ws_size, hipStream_t stream) {
  const float* state  = (const float*)d_in[0];
  const float* enc_w1 = (const float*)d_in[1];
  const float* enc_b1 = (const float*)d_in[2];
  const float* enc_w2 = (const float*)d_in[3];
  const float* enc_b2 = (const float*)d_in[4];
  const float* qparams= (const float*)d_in[5];
  const float* dec_w1 = (const float*)d_in[6];
  const float* dec_b1 = (const float*)d_in[7];
  const float* dec_w2 = (const float*)d_in[8];
  const float* dec_b2 = (const float*)d_in[9];
  const float* val_w1 = (const float*)d_in[10];
  const float* val_b1 = (const float*)d_in[11];
  const float* val_w2 = (const float*)d_in[12];
  const float* val_b2 = (const float*)d_in[13];

  float* wsf = (float*)d_ws;
  // ws layout (floats):
  float* dots_rep = wsf;                         // 32*128 = 4096
  float* xn2      = wsf + 4096;                  // 1
  float* L2acc    = wsf + 4097;                  // 1
  cplx*  Ug       = (cplx*)(wsf + 4352);         // 216 cplx (432 f)
  cplx*  prodLow  = (cplx*)(wsf + 8192);         // 4096 cplx (8192 f)
  cplx*  prodHigh = (cplx*)(wsf + 16384);        // 64 cplx (128 f)
  float* xRe      = wsf + 16640;                 // 73728
  float* xIm      = wsf + 90368;                 // 73728
  cplx*  svA      = (cplx*)(wsf + 164096);       // 262144 cplx
  cplx*  svB      = (cplx*)(wsf + 688384);       // 262144 cplx
  float* cl       = wsf + 1212672;               // 524288  (ends 1736960)

  hipLaunchKernelGGL(k_prep, dim3(1), dim3(256), 0, stream,
                     qparams, Ug, prodLow, prodHigh, wsf);
  hipLaunchKernelGGL(k_enc, dim3(1024), dim3(256), 0, stream,
                     state, enc_w1, enc_b1, enc_w2, enc_b2, xRe, xIm, xn2);
  // layer index 1: input = permuted layer-0 product state
  hipLaunchKernelGGL(k_gatesLow, dim3(256), dim3(512), 0, stream,
                     Ug, prodLow, prodHigh, (const cplx*)nullptr, svA, 1, 0);
  hipLaunchKernelGGL(k_gatesHigh, dim3(256), dim3(512), 0, stream, Ug, svA, 1);
  // layer index 2: input = svA gathered through perm P
  hipLaunchKernelGGL(k_gatesLow, dim3(256), dim3(512), 0, stream,
                     Ug, prodLow, prodHigh, (const cplx*)svA, svB, 2, 1);
  hipLaunchKernelGGL(k_gatesHigh, dim3(256), dim3(512), 0, stream, Ug, svB, 2);
  hipLaunchKernelGGL(k_combine, dim3(256), dim3(256), 0, stream,
                     svB, xRe, xIm, xn2, cl, L2acc);
  hipLaunchKernelGGL(k_matvec, dim3(2048), dim3(256), 0, stream,
                     cl, dec_w1, val_w1, dots_rep);
  hipLaunchKernelGGL(k_final, dim3(1), dim3(64), 0, stream,
                     dots_rep, L2acc, dec_b1, dec_w2, dec_b2,
                     val_b1, val_w2, val_b2, (float*)d_out);
}

// Round 2
// 355.302 us; speedup vs baseline: 1.0994x; 1.0975x over previous
//
#include <hip/hip_runtime.h>
#include <cstdint>
#include <cstddef>

// ---------------------------------------------------------------------------
// QuantumRLAgent: 18-qubit statevector sim + MLPs.
// Batch collapses into ONE statevector. Dominant cost: two 524288x64 fp32
// matvecs (268 MB weight stream). Circuit: fused 1q gates; CNOT chain ==
// perm P(i)=(i^(i<<1))&0x3FFFF fused into next kernel's gather; layer-1
// analytic product state.
//
// R5 -> R6: asm pipeline (VGPR 60, 16 loads in flight/wave) changed NOTHING
// vs 1-deep (105 vs 103 us) -> demand cap ~2.55 TB/s is a SERVICE-RATE
// limit, not latency/MLP. Suspect: L2/LLC allocation churn on a use-once
// 268 MB stream (268 MB cyclic vs 256 MB LLC = LRU-thrash; 50% hit is the
// wreckage; every L2 line alloc+evict at ~2.5 lines/cy/XCD). Experiment:
// `nt` (non-temporal, evict-first) on all 32 weight loads, rest identical.
// Predict: FETCH 133->~268 MB, hbm_gbps 1300->4500+, matvec 105->~50 us.
// If unchanged: cap is request-side -> pivot to global_load_lds.
// ---------------------------------------------------------------------------

#define NQb   18
#define DIMSZ 262144      // 2^18
#define PMASK 0x3FFFF
#define XLEN  73728       // 4096*18

typedef float2 cplx;
typedef float f4 __attribute__((ext_vector_type(4)));

__device__ __forceinline__ cplx cmul(cplx a, cplx b) {
  return make_float2(a.x*b.x - a.y*b.y, a.x*b.y + a.y*b.x);
}
__device__ __forceinline__ cplx cadd(cplx a, cplx b) {
  return make_float2(a.x + b.x, a.y + b.y);
}

// --------------------------------------------------------------------------
// K_prep: fused U = Rz*Ry*Rx per (layer,qubit); layer-0 product tables;
// zero accumulators (dots_rep[32][128] + xn2 + L2acc).
// --------------------------------------------------------------------------
__global__ void k_prep(const float* __restrict__ qp, cplx* __restrict__ Ug,
                       cplx* __restrict__ prodLow, cplx* __restrict__ prodHigh,
                       float* __restrict__ accs) {
  __shared__ cplx Ush[54][4];
  int t = threadIdx.x;
  for (int k = t; k < 4352; k += 256) accs[k] = 0.0f;
  if (t < 54) {
    float a = qp[t*3+0], b = qp[t*3+1], c = qp[t*3+2];
    float ca = cosf(0.5f*a), sa = sinf(0.5f*a);
    float cb = cosf(0.5f*b), sb = sinf(0.5f*b);
    float cc = cosf(0.5f*c), sc = sinf(0.5f*c);
    // M = Ry*Rx
    cplx m00 = make_float2( cb*ca,  sb*sa);
    cplx m01 = make_float2(-sb*ca, -cb*sa);
    cplx m10 = make_float2( sb*ca, -cb*sa);
    cplx m11 = make_float2( cb*ca, -sb*sa);
    // U = Rz*M : row0 *= e^{-ic/2}, row1 *= e^{+ic/2}
    cplx e0 = make_float2(cc, -sc), e1 = make_float2(cc, sc);
    cplx u00 = cmul(e0, m00), u01 = cmul(e0, m01);
    cplx u10 = cmul(e1, m10), u11 = cmul(e1, m11);
    Ush[t][0] = u00; Ush[t][1] = u01; Ush[t][2] = u10; Ush[t][3] = u11;
    Ug[t*4+0] = u00; Ug[t*4+1] = u01; Ug[t*4+2] = u10; Ug[t*4+3] = u11;
  }
  __syncthreads();
  // layer-0 product state: amp(i) = prod_p U0[17-p][bit_p(i)][0]
  for (int m = t; m < 4096; m += blockDim.x) {
    cplx v = make_float2(1.f, 0.f);
    for (int p = 0; p < 12; ++p) {
      int q = 17 - p;
      cplx f = ((m >> p) & 1) ? Ush[q][2] : Ush[q][0];
      v = cmul(v, f);
    }
    prodLow[m] = v;
  }
  if (t < 64) {
    cplx v = make_float2(1.f, 0.f);
    for (int p = 12; p < 18; ++p) {
      int q = 17 - p;
      cplx f = ((t >> (p - 12)) & 1) ? Ush[q][2] : Ush[q][0];
      v = cmul(v, f);
    }
    prodHigh[t] = v;
  }
}

// --------------------------------------------------------------------------
// K_enc: h = relu(state@w1+b1); enc = h@w2+b2; xc = amp*exp(i*ph).
// 1024 blocks x 256 threads, 4 rows/block, 4 independent accumulators.
// --------------------------------------------------------------------------
__global__ __launch_bounds__(256) void k_enc(
    const float* __restrict__ state, const float* __restrict__ w1,
    const float* __restrict__ b1, const float* __restrict__ w2,
    const float* __restrict__ b2, float* __restrict__ xRe,
    float* __restrict__ xIm, float* __restrict__ xn2) {
  __shared__ float sState[4][256];
  __shared__ float hS[4][64];
  __shared__ float encS[4][36];
  __shared__ float wsum[4];
  int t = threadIdx.x;
  int r = t >> 6, j = t & 63;
  const float4* st4 =
      reinterpret_cast<const float4*>(state + (size_t)blockIdx.x * 1024);
  reinterpret_cast<float4*>(&sState[0][0])[t] = st4[t];
  __syncthreads();
  float a0 = 0.f, a1 = 0.f, a2 = 0.f, a3 = 0.f;
#pragma unroll 4
  for (int k = 0; k < 256; k += 4) {
    a0 = fmaf(sState[r][k+0], w1[(k+0)*64 + j], a0);
    a1 = fmaf(sState[r][k+1], w1[(k+1)*64 + j], a1);
    a2 = fmaf(sState[r][k+2], w1[(k+2)*64 + j], a2);
    a3 = fmaf(sState[r][k+3], w1[(k+3)*64 + j], a3);
  }
  hS[r][j] = fmaxf((a0 + a1) + (a2 + a3) + b1[j], 0.f);
  __syncthreads();
  if (j < 36) {
    float a = b2[j];
#pragma unroll 8
    for (int k = 0; k < 64; ++k) a = fmaf(hS[r][k], w2[k*36 + j], a);
    encS[r][j] = a;
  }
  __syncthreads();
  float lsum = 0.f;
  if (j < 18) {
    float amp = encS[r][j], ph = encS[r][18 + j];
    float sp, cp;
    sincosf(ph, &sp, &cp);
    int row = blockIdx.x*4 + r;
    xRe[row*18 + j] = amp * cp;
    xIm[row*18 + j] = amp * sp;
    lsum = amp * amp;
  }
  for (int off = 32; off > 0; off >>= 1) lsum += __shfl_down(lsum, off, 64);
  if (j == 0) wsum[r] = lsum;
  __syncthreads();
  if (t == 0) atomicAdd(xn2, wsum[0] + wsum[1] + wsum[2] + wsum[3]);
}

// --------------------------------------------------------------------------
// K_gatesLow: gates on bits 0..9 (qubits 17..8). 256 blocks x 512 thr,
// contiguous 1024-elem tiles in LDS. Input gathered through perm P.
// mode 0: layer-0 product state; mode 1: svIn[P(i)].
// --------------------------------------------------------------------------
__global__ __launch_bounds__(512) void k_gatesLow(
    const cplx* __restrict__ Ug, const cplx* __restrict__ prodLow,
    const cplx* __restrict__ prodHigh, const cplx* __restrict__ svIn,
    cplx* __restrict__ svOut, int layer, int mode) {
  __shared__ float sRe[1024], sIm[1024];
  int t = threadIdx.x;
  int base = blockIdx.x << 10;
  for (int e = t; e < 1024; e += 512) {
    int i = base + e;
    int src = (i ^ (i << 1)) & PMASK;   // CNOT-chain permutation
    cplx v;
    if (mode == 0) v = cmul(prodHigh[src >> 12], prodLow[src & 4095]);
    else           v = svIn[src];
    sRe[e] = v.x; sIm[e] = v.y;
  }
  __syncthreads();
  for (int p = 0; p < 10; ++p) {
    int q = 17 - p;
    const cplx* U = Ug + (layer*18 + q)*4;
    cplx u00 = U[0], u01 = U[1], u10 = U[2], u11 = U[3];
    {
      int k = t;
      int i0 = ((k >> p) << (p + 1)) | (k & ((1 << p) - 1));
      int i1 = i0 | (1 << p);
      cplx a = make_float2(sRe[i0], sIm[i0]);
      cplx b = make_float2(sRe[i1], sIm[i1]);
      cplx na = cadd(cmul(u00, a), cmul(u01, b));
      cplx nb = cadd(cmul(u10, a), cmul(u11, b));
      sRe[i0] = na.x; sIm[i0] = na.y;
      sRe[i1] = nb.x; sIm[i1] = nb.y;
    }
    __syncthreads();
  }
  for (int e = t; e < 1024; e += 512)
    svOut[base + e] = make_float2(sRe[e], sIm[e]);
}

// --------------------------------------------------------------------------
// K_gatesHigh: gates on bits 10..17 (qubits 7..0). 256 blocks x 512 thr.
// Tile = 256 h-values (bits 10..17) x 4 l-values; in-place (tiles partition
// by l-chunk). LDS index m = h*4 + j.
// --------------------------------------------------------------------------
__global__ __launch_bounds__(512) void k_gatesHigh(
    const cplx* __restrict__ Ug, cplx* __restrict__ sv, int layer) {
  __shared__ float tRe[1024], tIm[1024];
  int t = threadIdx.x;
  int l0 = blockIdx.x << 2;
  for (int e = t; e < 1024; e += 512) {
    int h = e >> 2, j = e & 3;
    cplx v = sv[h*1024 + l0 + j];
    tRe[e] = v.x; tIm[e] = v.y;
  }
  __syncthreads();
  for (int ph = 0; ph < 8; ++ph) {
    int q = 7 - ph;                    // bit p = 10+ph, qubit q = 17-p
    const cplx* U = Ug + (layer*18 + q)*4;
    cplx u00 = U[0], u01 = U[1], u10 = U[2], u11 = U[3];
    {
      int kh = t >> 2, j = t & 3;
      int h0 = ((kh >> ph) << (ph + 1)) | (kh & ((1 << ph) - 1));
      int h1 = h0 | (1 << ph);
      int i0 = h0*4 + j, i1 = h1*4 + j;
      cplx a = make_float2(tRe[i0], tIm[i0]);
      cplx b = make_float2(tRe[i1], tIm[i1]);
      cplx na = cadd(cmul(u00, a), cmul(u01, b));
      cplx nb = cadd(cmul(u10, a), cmul(u11, b));
      tRe[i0] = na.x; tIm[i0] = na.y;
      tRe[i1] = nb.x; tIm[i1] = nb.y;
    }
    __syncthreads();
  }
  for (int e = t; e < 1024; e += 512) {
    int h = e >> 2, j = e & 3;
    sv[h*1024 + l0 + j] = make_float2(tRe[e], tIm[e]);
  }
}

// --------------------------------------------------------------------------
// K_combine: final perm gather + add normalized x + build cl (re plane,
// im plane; unnormalized) + accumulate L2 = ||sv||^2.
// --------------------------------------------------------------------------
__global__ __launch_bounds__(256) void k_combine(
    const cplx* __restrict__ svIn, const float* __restrict__ xRe,
    const float* __restrict__ xIm, const float* __restrict__ xn2,
    float* __restrict__ cl, float* __restrict__ L2acc) {
  int t = threadIdx.x;
  float xs = xn2[0];
  float invXn = (xs > 0.f) ? (1.0f / sqrtf(xs)) : 1.0f;
  float lsum = 0.f;
  for (int u = 0; u < 4; ++u) {
    int i = blockIdx.x*1024 + u*256 + t;
    int src = (i ^ (i << 1)) & PMASK;
    cplx v = svIn[src];
    if (i < XLEN) {
      v.x = fmaf(xRe[i], invXn, v.x);
      v.y = fmaf(xIm[i], invXn, v.y);
    }
    cl[i] = v.x;
    cl[DIMSZ + i] = v.y;
    lsum += v.x*v.x + v.y*v.y;
  }
  for (int off = 32; off > 0; off >>= 1) lsum += __shfl_down(lsum, off, 64);
  if ((t & 63) == 0) atomicAdd(L2acc, lsum);
}

// --------------------------------------------------------------------------
// K_matvec: partial[slot][mat*64+c] += sum_r cl[r]*W[r,c] over a 512-row
// chunk. 2048 blocks (1024 chunks x 2 mats).
//
// R6: R5's asm pipeline + `nt` (non-temporal / evict-first) on all weight
// loads. The weights are a use-once 268 MB stream that thrashes LLC
// (268 cyclic vs 256 MB) and churns L2 allocation; nt tells the cache
// hierarchy to stream it. Counted waits unchanged: vmcnt(8) retires the
// older group; "+v" ties + sched_barrier(0) fence the FMAs (rule #18).
// --------------------------------------------------------------------------
#define GLOAD(dst, ptr) \
  asm volatile("global_load_dwordx4 %0, %1, off nt" : "=v"(dst) : "v"(ptr))

#define VMWAIT(N, x0,x1,x2,x3,x4,x5,x6,x7) do {                      \
    asm volatile("s_waitcnt vmcnt(" #N ")"                           \
        : "+v"(x0), "+v"(x1), "+v"(x2), "+v"(x3),                    \
          "+v"(x4), "+v"(x5), "+v"(x6), "+v"(x7));                   \
    __builtin_amdgcn_sched_barrier(0);                               \
  } while (0)

#define CONSUME(g, w0,w1,w2,w3,w4,w5,w6,w7) do {                     \
    const int rr = (g)*128 + ro;                                     \
    float s0 = clS[rr+  0], s1 = clS[rr+ 16];                        \
    float s2 = clS[rr+ 32], s3 = clS[rr+ 48];                        \
    float s4 = clS[rr+ 64], s5 = clS[rr+ 80];                        \
    float s6 = clS[rr+ 96], s7 = clS[rr+112];                        \
    ax = fmaf(s0, w0[0], ax); ay = fmaf(s0, w0[1], ay);              \
    az = fmaf(s0, w0[2], az); aw = fmaf(s0, w0[3], aw);              \
    ax = fmaf(s1, w1[0], ax); ay = fmaf(s1, w1[1], ay);              \
    az = fmaf(s1, w1[2], az); aw = fmaf(s1, w1[3], aw);              \
    ax = fmaf(s2, w2[0], ax); ay = fmaf(s2, w2[1], ay);              \
    az = fmaf(s2, w2[2], az); aw = fmaf(s2, w2[3], aw);              \
    ax = fmaf(s3, w3[0], ax); ay = fmaf(s3, w3[1], ay);              \
    az = fmaf(s3, w3[2], az); aw = fmaf(s3, w3[3], aw);              \
    ax = fmaf(s4, w4[0], ax); ay = fmaf(s4, w4[1], ay);              \
    az = fmaf(s4, w4[2], az); aw = fmaf(s4, w4[3], aw);              \
    ax = fmaf(s5, w5[0], ax); ay = fmaf(s5, w5[1], ay);              \
    az = fmaf(s5, w5[2], az); aw = fmaf(s5, w5[3], aw);              \
    ax = fmaf(s6, w6[0], ax); ay = fmaf(s6, w6[1], ay);              \
    az = fmaf(s6, w6[2], az); aw = fmaf(s6, w6[3], aw);              \
    ax = fmaf(s7, w7[0], ax); ay = fmaf(s7, w7[1], ay);              \
    az = fmaf(s7, w7[2], az); aw = fmaf(s7, w7[3], aw);              \
  } while (0)

__global__ __launch_bounds__(256) void k_matvec(
    const float* __restrict__ cl, const float* __restrict__ Wdec,
    const float* __restrict__ Wval, float* __restrict__ dots_rep) {
  __shared__ float clS[512];
  __shared__ float red[1024];
  int t = threadIdx.x;
  int mat = blockIdx.x & 1;
  int chunk = blockIdx.x >> 1;             // 0..1023
  size_t r0 = (size_t)chunk * 512;
  if (t < 128)
    reinterpret_cast<float4*>(clS)[t] =
        reinterpret_cast<const float4*>(cl + r0)[t];
  __syncthreads();
  const float* Wb = (mat ? Wval : Wdec) + r0*64 + (size_t)((t & 15)*4);
  const int ro = t >> 4;
  // 8 row-phase base pointers (row stride within a group = 16 rows = 1024 f)
  const float* p0 = Wb + (size_t)ro * 64;
  const float* p1 = p0 + 1024;
  const float* p2 = p0 + 2048;
  const float* p3 = p0 + 3072;
  const float* p4 = p0 + 4096;
  const float* p5 = p0 + 5120;
  const float* p6 = p0 + 6144;
  const float* p7 = p0 + 7168;
  float ax = 0.f, ay = 0.f, az = 0.f, aw = 0.f;
  f4 A0, A1, A2, A3, A4, A5, A6, A7;
  f4 B0, B1, B2, B3, B4, B5, B6, B7;
  // group stride = 128 rows = 8192 floats
  // ---- prologue: issue g0, g1 (16 loads in flight) ----
  GLOAD(A0, p0);        GLOAD(A1, p1);        GLOAD(A2, p2);
  GLOAD(A3, p3);        GLOAD(A4, p4);        GLOAD(A5, p5);
  GLOAD(A6, p6);        GLOAD(A7, p7);
  GLOAD(B0, p0 + 8192); GLOAD(B1, p1 + 8192); GLOAD(B2, p2 + 8192);
  GLOAD(B3, p3 + 8192); GLOAD(B4, p4 + 8192); GLOAD(B5, p5 + 8192);
  GLOAD(B6, p6 + 8192); GLOAD(B7, p7 + 8192);
  // ---- g0: wait for A (B stays in flight), consume, refill A with g2 ----
  VMWAIT(8, A0, A1, A2, A3, A4, A5, A6, A7);
  CONSUME(0, A0, A1, A2, A3, A4, A5, A6, A7);
  GLOAD(A0, p0 + 16384); GLOAD(A1, p1 + 16384); GLOAD(A2, p2 + 16384);
  GLOAD(A3, p3 + 16384); GLOAD(A4, p4 + 16384); GLOAD(A5, p5 + 16384);
  GLOAD(A6, p6 + 16384); GLOAD(A7, p7 + 16384);
  // ---- g1: wait for B, consume, refill B with g3 ----
  VMWAIT(8, B0, B1, B2, B3, B4, B5, B6, B7);
  CONSUME(1, B0, B1, B2, B3, B4, B5, B6, B7);
  GLOAD(B0, p0 + 24576); GLOAD(B1, p1 + 24576); GLOAD(B2, p2 + 24576);
  GLOAD(B3, p3 + 24576); GLOAD(B4, p4 + 24576); GLOAD(B5, p5 + 24576);
  GLOAD(B6, p6 + 24576); GLOAD(B7, p7 + 24576);
  // ---- g2 ----
  VMWAIT(8, A0, A1, A2, A3, A4, A5, A6, A7);
  CONSUME(2, A0, A1, A2, A3, A4, A5, A6, A7);
  // ---- g3 (tail: drain) ----
  VMWAIT(0, B0, B1, B2, B3, B4, B5, B6, B7);
  CONSUME(3, B0, B1, B2, B3, B4, B5, B6, B7);

  red[t*4+0] = ax; red[t*4+1] = ay; red[t*4+2] = az; red[t*4+3] = aw;
  __syncthreads();
  if (t < 64) {
    int ci0 = t >> 2, jj = t & 3;
    float sum = 0.f;
#pragma unroll
    for (int r2 = 0; r2 < 16; ++r2) sum += red[(r2*16 + ci0)*4 + jj];
    int slot = chunk & 31;
    atomicAdd(&dots_rep[slot*128 + mat*64 + t], sum);
  }
}

// --------------------------------------------------------------------------
// K_final: sum 32 slots, apply invL, hidden relu + tiny second layers.
// --------------------------------------------------------------------------
__global__ void k_final(const float* __restrict__ dots_rep,
                        const float* __restrict__ L2acc,
                        const float* __restrict__ db1,
                        const float* __restrict__ dw2,
                        const float* __restrict__ db2,
                        const float* __restrict__ vb1,
                        const float* __restrict__ vw2,
                        const float* __restrict__ vb2,
                        float* __restrict__ out) {
  __shared__ float hd[64], hv[64];
  int t = threadIdx.x;
  float sd = 0.f, sva = 0.f;
#pragma unroll
  for (int s = 0; s < 32; ++s) {
    sd  += dots_rep[s*128 + t];
    sva += dots_rep[s*128 + 64 + t];
  }
  float invL = 1.0f / sqrtf(L2acc[0]);
  hd[t] = fmaxf(sd * invL + db1[t], 0.f);
  hv[t] = fmaxf(sva * invL + vb1[t], 0.f);
  __syncthreads();
  if (t < 18) {
    float s = db2[t];
    for (int k = 0; k < 64; ++k) s = fmaf(hd[k], dw2[k*18 + t], s);
    out[t] = s;
  }
  if (t == 20) {
    float s = vb2[0];
    for (int k = 0; k < 64; ++k) s = fmaf(hv[k], vw2[k], s);
    out[18] = s;
  }
}

extern "C" void kernel_launch(void* const* d_in, const int* in_sizes, int n_in,
                              void* d_out, int out_size, void* d_ws,
                              size_t ws_size, hipStream_t stream) {
  const float* state  = (const float*)d_in[0];
  const float* enc_w1 = (const float*)d_in[1];
  const float* enc_b1 = (const float*)d_in[2];
  const float* enc_w2 = (const float*)d_in[3];
  const float* enc_b2 = (const float*)d_in[4];
  const float* qparams= (const float*)d_in[5];
  const float* dec_w1 = (const float*)d_in[6];
  const float* dec_b1 = (const float*)d_in[7];
  const float* dec_w2 = (const float*)d_in[8];
  const float* dec_b2 = (const float*)d_in[9];
  const float* val_w1 = (const float*)d_in[10];
  const float* val_b1 = (const float*)d_in[11];
  const float* val_w2 = (const float*)d_in[12];
  const float* val_b2 = (const float*)d_in[13];

  float* wsf = (float*)d_ws;
  // ws layout (floats):
  float* dots_rep = wsf;                         // 32*128 = 4096
  float* xn2      = wsf + 4096;                  // 1
  float* L2acc    = wsf + 4097;                  // 1
  cplx*  Ug       = (cplx*)(wsf + 4352);         // 216 cplx (432 f)
  cplx*  prodLow  = (cplx*)(wsf + 8192);         // 4096 cplx (8192 f)
  cplx*  prodHigh = (cplx*)(wsf + 16384);        // 64 cplx (128 f)
  float* xRe      = wsf + 16640;                 // 73728
  float* xIm      = wsf + 90368;                 // 73728
  cplx*  svA      = (cplx*)(wsf + 164096);       // 262144 cplx
  cplx*  svB      = (cplx*)(wsf + 688384);       // 262144 cplx
  float* cl       = wsf + 1212672;               // 524288  (ends 1736960)

  hipLaunchKernelGGL(k_prep, dim3(1), dim3(256), 0, stream,
                     qparams, Ug, prodLow, prodHigh, wsf);
  hipLaunchKernelGGL(k_enc, dim3(1024), dim3(256), 0, stream,
                     state, enc_w1, enc_b1, enc_w2, enc_b2, xRe, xIm, xn2);
  // layer index 1: input = permuted layer-0 product state
  hipLaunchKernelGGL(k_gatesLow, dim3(256), dim3(512), 0, stream,
                     Ug, prodLow, prodHigh, (const cplx*)nullptr, svA, 1, 0);
  hipLaunchKernelGGL(k_gatesHigh, dim3(256), dim3(512), 0, stream, Ug, svA, 1);
  // layer index 2: input = svA gathered through perm P
  hipLaunchKernelGGL(k_gatesLow, dim3(256), dim3(512), 0, stream,
                     Ug, prodLow, prodHigh, (const cplx*)svA, svB, 2, 1);
  hipLaunchKernelGGL(k_gatesHigh, dim3(256), dim3(512), 0, stream, Ug, svB, 2);
  hipLaunchKernelGGL(k_combine, dim3(256), dim3(256), 0, stream,
                     svB, xRe, xIm, xn2, cl, L2acc);
  hipLaunchKernelGGL(k_matvec, dim3(2048), dim3(256), 0, stream,
                     cl, dec_w1, val_w1, dots_rep);
  hipLaunchKernelGGL(k_final, dim3(1), dim3(64), 0, stream,
                     dots_rep, L2acc, dec_b1, dec_w2, dec_b2,
                     val_b1, val_w2, val_b2, (float*)d_out);
}